// Round 5
// baseline (465.973 us; speedup 1.0000x reference)
//
#include <hip/hip_runtime.h>
#include <hip/hip_fp16.h>

#define NFEAT 128
#define NHID 64
#define MAXB 1024          // max dst buckets (node>>8), supports N<=262144
#define BSHIFT 8
#define BNODES 256

// ---------- edge-index dtype detection ----------
// JAX reference says int64 but default JAX config downcasts to int32.
// Little-endian int64 with values < 2^31 => every odd int32 word is 0.
__global__ void k_detect(const int* __restrict__ ei_words, int nwords, int* flag) {
    __shared__ int s_or;
    if (threadIdx.x == 0) s_or = 0;
    __syncthreads();
    int acc = 0;
    for (int i = 1 + 2 * (int)threadIdx.x; i < nwords; i += 2 * (int)blockDim.x)
        acc |= ei_words[i];
    atomicOr(&s_or, acc);
    __syncthreads();
    if (threadIdx.x == 0) *flag = (s_or == 0) ? 1 : 0;
}

__device__ __forceinline__ int edge_idx(const int* __restrict__ ei, int is64,
                                        long long E, long long e, int which) {
    long long pos = which ? (E + e) : e;
    return is64 ? ei[2 * pos] : ei[pos];
}

// ---------- bucket histogram (LDS-privatized) ----------
__global__ __launch_bounds__(256) void k_bhist(const int* __restrict__ ei,
                                               const int* __restrict__ flag,
                                               long long E, int* gbhist, int NB) {
    __shared__ int hist[MAXB];
    for (int i = threadIdx.x; i < NB; i += 256) hist[i] = 0;
    __syncthreads();
    int is64 = *flag;
    long long stride = (long long)gridDim.x * 256;
    for (long long e = (long long)blockIdx.x * 256 + threadIdx.x; e < E; e += stride) {
        int d = edge_idx(ei, is64, E, e, 1);
        atomicAdd(&hist[d >> BSHIFT], 1);
    }
    __syncthreads();
    for (int i = threadIdx.x; i < NB; i += 256)
        if (hist[i]) atomicAdd(&gbhist[i], hist[i]);
}

// ---------- scan bucket totals (1 block); also writes off[N]=E ----------
__global__ __launch_bounds__(256) void k_bscan(const int* __restrict__ gbhist, int NB,
                                               int* boff, int* bcur, int* offN) {
    __shared__ int s[256];
    int t = threadIdx.x;
    int v[4]; int sum = 0;
#pragma unroll
    for (int j = 0; j < 4; ++j) {
        int i = t * 4 + j;
        v[j] = (i < NB) ? gbhist[i] : 0;
        sum += v[j];
    }
    s[t] = sum;
    __syncthreads();
    for (int d = 1; d < 256; d <<= 1) {
        int val = (t >= d) ? s[t - d] : 0;
        __syncthreads();
        s[t] += val;
        __syncthreads();
    }
    int run = s[t] - sum;   // exclusive
#pragma unroll
    for (int j = 0; j < 4; ++j) {
        int i = t * 4 + j;
        if (i <= NB) boff[i] = run;
        if (i < NB)  bcur[i] = run;
        run += v[j];
    }
    if (t == 255) *offN = s[255];   // off[N] = E
}

// ---------- partition edges into dst buckets (LDS cursors, packed 4B records) ----------
// record = src | (dst&255)<<24  (requires src < 2^24)
__global__ __launch_bounds__(256) void k_partition(const int* __restrict__ ei,
                                                   const int* __restrict__ flag,
                                                   long long E, int* bcur,
                                                   unsigned* __restrict__ staging,
                                                   int NB, long long perblk) {
    __shared__ int hist[MAXB];
    __shared__ int cur[MAXB];
    for (int i = threadIdx.x; i < NB; i += 256) hist[i] = 0;
    __syncthreads();
    long long lo = (long long)blockIdx.x * perblk;
    long long hi = lo + perblk; if (hi > E) hi = E;
    int is64 = *flag;
    for (long long e = lo + threadIdx.x; e < hi; e += 256) {
        int d = edge_idx(ei, is64, E, e, 1);
        atomicAdd(&hist[d >> BSHIFT], 1);
    }
    __syncthreads();
    for (int i = threadIdx.x; i < NB; i += 256)
        cur[i] = hist[i] ? atomicAdd(&bcur[i], hist[i]) : 0;
    __syncthreads();
    for (long long e = lo + threadIdx.x; e < hi; e += 256) {
        int s = edge_idx(ei, is64, E, e, 0);
        int d = edge_idx(ei, is64, E, e, 1);
        int pos = atomicAdd(&cur[d >> BSHIFT], 1);
        staging[pos] = (unsigned)s | ((unsigned)(d & (BNODES - 1)) << 24);
    }
}

// ---------- per-bucket CSR: node counts, scan, fill esrc; emit off & dinv ----------
__global__ __launch_bounds__(256) void k_bucket(const unsigned* __restrict__ staging,
                                                const int* __restrict__ boff,
                                                int N, int* off, int* esrc, float* dinv) {
    __shared__ int cnt_s[BNODES];
    __shared__ int scan_s[BNODES];
    int b = blockIdx.x;
    int base = b << BSHIFT;
    int t = threadIdx.x;
    cnt_s[t] = 0;
    __syncthreads();
    int lo = boff[b], hi = boff[b + 1];
    for (int e = lo + t; e < hi; e += 256)
        atomicAdd(&cnt_s[staging[e] >> 24], 1);
    __syncthreads();
    int v = cnt_s[t];
    scan_s[t] = v;
    __syncthreads();
    for (int d = 1; d < 256; d <<= 1) {
        int val = (t >= d) ? scan_s[t - d] : 0;
        __syncthreads();
        scan_s[t] += val;
        __syncthreads();
    }
    int excl = scan_s[t] - v;
    int node = base + t;
    if (node < N) {
        off[node] = lo + excl;
        dinv[node] = rsqrtf((float)v + 1.0f);   // +1 self loop
    }
    __syncthreads();
    cnt_s[t] = lo + excl;   // reuse as cursor
    __syncthreads();
    for (int e = lo + t; e < hi; e += 256) {
        unsigned sd = staging[e];
        int pos = atomicAdd(&cnt_s[sd >> 24], 1);
        esrc[pos] = (int)(sd & 0xFFFFFFu);
    }
}

// ---------- register-blocked fp32 GEMM helpers ----------
__device__ __forceinline__ void fma4(float (&acc)[4], float a, const float4& b) {
    acc[0] += a * b.x; acc[1] += a * b.y; acc[2] += a * b.z; acc[3] += a * b.w;
}

// ---------- GEMM1: x[N,128] @ W1[128,64], scaled by dinv[row] -> xw1s[N,64] fp16 ----------
__global__ __launch_bounds__(256) void k_gemm1(const float* __restrict__ x,
                                               const float* __restrict__ W1,
                                               const float* __restrict__ dinv,
                                               __half* __restrict__ xw1s, int N) {
    __shared__ float sA[64 * NFEAT];   // 32 KB
    __shared__ float sB[NFEAT * NHID]; // 32 KB
    for (int i = threadIdx.x; i < NFEAT * NHID / 4; i += 256)
        ((float4*)sB)[i] = ((const float4*)W1)[i];
    int row0 = blockIdx.x * 64;
    for (int i = threadIdx.x; i < 64 * NFEAT / 4; i += 256) {
        int r = i >> 5, c4 = i & 31;
        int row = row0 + r;
        ((float4*)sA)[i] = (row < N) ? ((const float4*)x)[(long long)row * 32 + c4]
                                     : make_float4(0.f, 0.f, 0.f, 0.f);
    }
    __syncthreads();
    int rg = threadIdx.x >> 4;
    int cg = threadIdx.x & 15;
    int r0 = rg * 4, c0 = cg * 4;
    float acc[4][4] = {};
#pragma unroll 4
    for (int k = 0; k < NFEAT; k += 4) {
        float4 a0 = *(const float4*)&sA[(r0 + 0) * NFEAT + k];
        float4 a1 = *(const float4*)&sA[(r0 + 1) * NFEAT + k];
        float4 a2 = *(const float4*)&sA[(r0 + 2) * NFEAT + k];
        float4 a3 = *(const float4*)&sA[(r0 + 3) * NFEAT + k];
        float4 b0 = *(const float4*)&sB[(k + 0) * NHID + c0];
        float4 b1 = *(const float4*)&sB[(k + 1) * NHID + c0];
        float4 b2v = *(const float4*)&sB[(k + 2) * NHID + c0];
        float4 b3 = *(const float4*)&sB[(k + 3) * NHID + c0];
        fma4(acc[0], a0.x, b0); fma4(acc[0], a0.y, b1); fma4(acc[0], a0.z, b2v); fma4(acc[0], a0.w, b3);
        fma4(acc[1], a1.x, b0); fma4(acc[1], a1.y, b1); fma4(acc[1], a1.z, b2v); fma4(acc[1], a1.w, b3);
        fma4(acc[2], a2.x, b0); fma4(acc[2], a2.y, b1); fma4(acc[2], a2.z, b2v); fma4(acc[2], a2.w, b3);
        fma4(acc[3], a3.x, b0); fma4(acc[3], a3.y, b1); fma4(acc[3], a3.z, b2v); fma4(acc[3], a3.w, b3);
    }
#pragma unroll
    for (int r = 0; r < 4; ++r) {
        int row = row0 + r0 + r;
        if (row < N) {
            float di = dinv[row];
            __half2* dst = (__half2*)&xw1s[(long long)row * NHID + c0];
            dst[0] = __floats2half2_rn(di * acc[r][0], di * acc[r][1]);
            dst[1] = __floats2half2_rn(di * acc[r][2], di * acc[r][3]);
        }
    }
}

// ---------- gather one node's aggregated (pre-scaled) feature sum ----------
// feat2: node rows of 32 half2. Lanes 0-31 process even edges, 32-63 odd.
// Returns float2 of feats (2*li, 2*li+1), valid in lanes 0..31 (li=lane&31).
// Self-loop included.
__device__ __forceinline__ float2 gather_node(const int* __restrict__ off,
                                              const int* __restrict__ esrc,
                                              const __half2* __restrict__ feat2,
                                              int d, int lane) {
    int lo = off[d], hi = off[d + 1];
    int sel = lane >> 5, li = lane & 31;
    float ax = 0.f, ay = 0.f;
    int e = lo;
    for (; e + 8 <= hi; e += 8) {
#pragma unroll
        for (int j = 0; j < 4; ++j) {
            int s = esrc[e + 2 * j + sel];
            float2 v = __half22float2(feat2[(long long)s * 32 + li]);
            ax += v.x; ay += v.y;
        }
    }
    for (; e + 2 <= hi; e += 2) {
        int s = esrc[e + sel];
        float2 v = __half22float2(feat2[(long long)s * 32 + li]);
        ax += v.x; ay += v.y;
    }
    if (e < hi && sel == 0) {
        float2 v = __half22float2(feat2[(long long)esrc[e] * 32 + li]);
        ax += v.x; ay += v.y;
    }
    ax += __shfl_xor(ax, 32);
    ay += __shfl_xor(ay, 32);
    float2 sv = __half22float2(feat2[(long long)d * 32 + li]);   // self loop
    return make_float2(ax + sv.x, ay + sv.y);
}

// ---------- layer-1 aggregation: bias+relu, output pre-scaled fp16 h ----------
__global__ __launch_bounds__(256) void k_agg1(const int* __restrict__ off,
                                              const int* __restrict__ esrc,
                                              const float* __restrict__ dinv,
                                              const __half2* __restrict__ xw1s2,
                                              const float* __restrict__ b1,
                                              __half2* __restrict__ h2, int N) {
    int wave = threadIdx.x >> 6;
    int lane = threadIdx.x & 63;
    int d = blockIdx.x * 4 + wave;
    if (d >= N) return;
    float2 a = gather_node(off, esrc, xw1s2, d, lane);
    if (lane < 32) {
        float dd = dinv[d];
        float2 bias = *(const float2*)&b1[2 * lane];
        float vx = fmaxf(dd * a.x + bias.x, 0.f);
        float vy = fmaxf(dd * a.y + bias.y, 0.f);
        h2[(long long)d * 32 + lane] = __floats2half2_rn(dd * vx, dd * vy);  // pre-scaled
    }
}

// ---------- fused layer-2 aggregation + GEMM2 ----------
// Per 64-node tile: waves gather agg rows into LDS sA (fp32), then block does
// sA[64,64] @ W2[64,128] + b2 -> out tile.
__global__ __launch_bounds__(256) void k_agg2_gemm2(const int* __restrict__ off,
                                                    const int* __restrict__ esrc,
                                                    const float* __restrict__ dinv,
                                                    const __half2* __restrict__ h2,
                                                    const float* __restrict__ W2,
                                                    const float* __restrict__ b2,
                                                    float* __restrict__ out,
                                                    int N, int ntiles) {
    __shared__ float sW[NHID * NFEAT]; // 32 KB
    __shared__ float sA[64 * NHID];    // 16 KB
    for (int i = threadIdx.x; i < NHID * NFEAT / 4; i += 256)
        ((float4*)sW)[i] = ((const float4*)W2)[i];
    int wave = threadIdx.x >> 6;
    int lane = threadIdx.x & 63;
    int rg = threadIdx.x >> 5;
    int cg = threadIdx.x & 31;
    int c0 = cg * 4;
    float4 bias = *(const float4*)&b2[c0];
    for (int tile = blockIdx.x; tile < ntiles; tile += gridDim.x) {
        int row0 = tile * 64;
        __syncthreads();   // protect sA from previous tile's GEMM reads
#pragma unroll 1
        for (int i = 0; i < 16; ++i) {
            int lr = wave * 16 + i;
            int d = row0 + lr;
            if (d < N) {
                float2 a = gather_node(off, esrc, h2, d, lane);
                if (lane < 32) {
                    float dd = dinv[d];
                    *(float2*)&sA[lr * NHID + 2 * lane] = make_float2(dd * a.x, dd * a.y);
                }
            } else if (lane < 32) {
                *(float2*)&sA[lr * NHID + 2 * lane] = make_float2(0.f, 0.f);
            }
        }
        __syncthreads();
        float acc[8][4] = {};
#pragma unroll 2
        for (int k = 0; k < NHID; k += 4) {
            float4 b0 = *(const float4*)&sW[(k + 0) * NFEAT + c0];
            float4 b1v = *(const float4*)&sW[(k + 1) * NFEAT + c0];
            float4 b2f = *(const float4*)&sW[(k + 2) * NFEAT + c0];
            float4 b3 = *(const float4*)&sW[(k + 3) * NFEAT + c0];
#pragma unroll
            for (int r = 0; r < 8; ++r) {
                float4 a = *(const float4*)&sA[(rg * 8 + r) * NHID + k];
                fma4(acc[r], a.x, b0); fma4(acc[r], a.y, b1v);
                fma4(acc[r], a.z, b2f); fma4(acc[r], a.w, b3);
            }
        }
#pragma unroll
        for (int r = 0; r < 8; ++r) {
            int row = row0 + rg * 8 + r;
            if (row < N) {
                float4 o = make_float4(acc[r][0] + bias.x, acc[r][1] + bias.y,
                                       acc[r][2] + bias.z, acc[r][3] + bias.w);
                *(float4*)&out[(long long)row * NFEAT + c0] = o;
            }
        }
    }
}

extern "C" void kernel_launch(void* const* d_in, const int* in_sizes, int n_in,
                              void* d_out, int out_size, void* d_ws, size_t ws_size,
                              hipStream_t stream) {
    const float* x  = (const float*)d_in[0];
    const int*   ei = (const int*)d_in[1];
    const float* W1 = (const float*)d_in[2];
    const float* b1 = (const float*)d_in[3];
    const float* W2 = (const float*)d_in[4];
    const float* b2 = (const float*)d_in[5];
    float* out = (float*)d_out;

    const int N = in_sizes[0] / NFEAT;            // 100000
    const long long E = in_sizes[1] / 2;          // 1600000
    const int NB = (N + BNODES - 1) >> BSHIFT;    // 391 buckets

    // workspace layout
    char* w = (char*)d_ws;
    int*      flag    = (int*)w;                       // pad 256 B
    int*      gbhist  = (int*)(w + 256);               // MAXB
    int*      boff    = gbhist + MAXB;                 // MAXB+1
    int*      bcur    = boff + MAXB + 1;               // MAXB
    float*    dinv    = (float*)(bcur + MAXB);         // N
    int*      off     = (int*)(dinv + N);              // N+1
    char*     p       = (char*)(off + N + 1);
    p = (char*)(((uintptr_t)p + 255) & ~(uintptr_t)255);
    unsigned* staging = (unsigned*)p;                  // E * 4 B
    int*      esrc    = (int*)(staging + E);           // E
    __half*   xw1s    = (__half*)(esrc + E);           // N*64 fp16
    __half*   h       = xw1s + (size_t)N * NHID;       // N*64 fp16

    hipMemsetAsync(gbhist, 0, (size_t)NB * sizeof(int), stream);

    k_detect<<<1, 256, 0, stream>>>(ei, 4096, flag);
    k_bhist<<<256, 256, 0, stream>>>(ei, flag, E, gbhist, NB);
    k_bscan<<<1, 256, 0, stream>>>(gbhist, NB, boff, bcur, off + N);
    long long perblk = (E + 511) / 512;
    k_partition<<<512, 256, 0, stream>>>(ei, flag, E, bcur, staging, NB, perblk);
    k_bucket<<<NB, 256, 0, stream>>>(staging, boff, N, off, esrc, dinv);

    k_gemm1<<<(N + 63) / 64, 256, 0, stream>>>(x, W1, dinv, xw1s, N);

    k_agg1<<<(N + 3) / 4, 256, 0, stream>>>(off, esrc, dinv, (const __half2*)xw1s,
                                            b1, (__half2*)h, N);

    int ntiles = (N + 63) / 64;
    int g2grid = ntiles < 768 ? ntiles : 768;
    k_agg2_gemm2<<<g2grid, 256, 0, stream>>>(off, esrc, dinv, (const __half2*)h,
                                             W2, b2, out, N, ntiles);
}

// Round 6
// 363.103 us; speedup vs baseline: 1.2833x; 1.2833x over previous
//
#include <hip/hip_runtime.h>
#include <hip/hip_fp16.h>

#define NFEAT 128
#define NHID 64
#define MAXB 1024          // max dst buckets (node>>8), supports N<=262144
#define BSHIFT 8
#define BNODES 256

// ---------- edge-index dtype detection ----------
// JAX reference says int64 but default JAX config downcasts to int32.
// Little-endian int64 with values < 2^31 => every odd int32 word is 0.
__global__ void k_detect(const int* __restrict__ ei_words, int nwords, int* flag) {
    __shared__ int s_or;
    if (threadIdx.x == 0) s_or = 0;
    __syncthreads();
    int acc = 0;
    for (int i = 1 + 2 * (int)threadIdx.x; i < nwords; i += 2 * (int)blockDim.x)
        acc |= ei_words[i];
    atomicOr(&s_or, acc);
    __syncthreads();
    if (threadIdx.x == 0) *flag = (s_or == 0) ? 1 : 0;
}

__device__ __forceinline__ int edge_idx(const int* __restrict__ ei, int is64,
                                        long long E, long long e, int which) {
    long long pos = which ? (E + e) : e;
    return is64 ? ei[2 * pos] : ei[pos];
}

// ---------- bucket histogram (LDS-privatized) ----------
__global__ __launch_bounds__(256) void k_bhist(const int* __restrict__ ei,
                                               const int* __restrict__ flag,
                                               long long E, int* gbhist, int NB) {
    __shared__ int hist[MAXB];
    for (int i = threadIdx.x; i < NB; i += 256) hist[i] = 0;
    __syncthreads();
    int is64 = *flag;
    long long stride = (long long)gridDim.x * 256;
    for (long long e = (long long)blockIdx.x * 256 + threadIdx.x; e < E; e += stride) {
        int d = edge_idx(ei, is64, E, e, 1);
        atomicAdd(&hist[d >> BSHIFT], 1);
    }
    __syncthreads();
    for (int i = threadIdx.x; i < NB; i += 256)
        if (hist[i]) atomicAdd(&gbhist[i], hist[i]);
}

// ---------- scan bucket totals (1 block); also writes off[N]=E ----------
__global__ __launch_bounds__(256) void k_bscan(const int* __restrict__ gbhist, int NB,
                                               int* boff, int* bcur, int* offN) {
    __shared__ int s[256];
    int t = threadIdx.x;
    int v[4]; int sum = 0;
#pragma unroll
    for (int j = 0; j < 4; ++j) {
        int i = t * 4 + j;
        v[j] = (i < NB) ? gbhist[i] : 0;
        sum += v[j];
    }
    s[t] = sum;
    __syncthreads();
    for (int d = 1; d < 256; d <<= 1) {
        int val = (t >= d) ? s[t - d] : 0;
        __syncthreads();
        s[t] += val;
        __syncthreads();
    }
    int run = s[t] - sum;   // exclusive
#pragma unroll
    for (int j = 0; j < 4; ++j) {
        int i = t * 4 + j;
        if (i <= NB) boff[i] = run;
        if (i < NB)  bcur[i] = run;
        run += v[j];
    }
    if (t == 255) *offN = s[255];   // off[N] = E
}

// ---------- partition edges into dst buckets (LDS cursors, packed 4B records) ----------
// record = src | (dst&255)<<24  (requires src < 2^24)
__global__ __launch_bounds__(256) void k_partition(const int* __restrict__ ei,
                                                   const int* __restrict__ flag,
                                                   long long E, int* bcur,
                                                   unsigned* __restrict__ staging,
                                                   int NB, long long perblk) {
    __shared__ int hist[MAXB];
    __shared__ int cur[MAXB];
    for (int i = threadIdx.x; i < NB; i += 256) hist[i] = 0;
    __syncthreads();
    long long lo = (long long)blockIdx.x * perblk;
    long long hi = lo + perblk; if (hi > E) hi = E;
    int is64 = *flag;
    for (long long e = lo + threadIdx.x; e < hi; e += 256) {
        int d = edge_idx(ei, is64, E, e, 1);
        atomicAdd(&hist[d >> BSHIFT], 1);
    }
    __syncthreads();
    for (int i = threadIdx.x; i < NB; i += 256)
        cur[i] = hist[i] ? atomicAdd(&bcur[i], hist[i]) : 0;
    __syncthreads();
    for (long long e = lo + threadIdx.x; e < hi; e += 256) {
        int s = edge_idx(ei, is64, E, e, 0);
        int d = edge_idx(ei, is64, E, e, 1);
        int pos = atomicAdd(&cur[d >> BSHIFT], 1);
        staging[pos] = (unsigned)s | ((unsigned)(d & (BNODES - 1)) << 24);
    }
}

// ---------- per-bucket CSR: node counts, scan, fill esrc; emit off & dinv ----------
__global__ __launch_bounds__(256) void k_bucket(const unsigned* __restrict__ staging,
                                                const int* __restrict__ boff,
                                                int N, int* off, int* esrc, float* dinv) {
    __shared__ int cnt_s[BNODES];
    __shared__ int scan_s[BNODES];
    int b = blockIdx.x;
    int base = b << BSHIFT;
    int t = threadIdx.x;
    cnt_s[t] = 0;
    __syncthreads();
    int lo = boff[b], hi = boff[b + 1];
    for (int e = lo + t; e < hi; e += 256)
        atomicAdd(&cnt_s[staging[e] >> 24], 1);
    __syncthreads();
    int v = cnt_s[t];
    scan_s[t] = v;
    __syncthreads();
    for (int d = 1; d < 256; d <<= 1) {
        int val = (t >= d) ? scan_s[t - d] : 0;
        __syncthreads();
        scan_s[t] += val;
        __syncthreads();
    }
    int excl = scan_s[t] - v;
    int node = base + t;
    if (node < N) {
        off[node] = lo + excl;
        dinv[node] = rsqrtf((float)v + 1.0f);   // +1 self loop
    }
    __syncthreads();
    cnt_s[t] = lo + excl;   // reuse as cursor
    __syncthreads();
    for (int e = lo + t; e < hi; e += 256) {
        unsigned sd = staging[e];
        int pos = atomicAdd(&cnt_s[sd >> 24], 1);
        esrc[pos] = (int)(sd & 0xFFFFFFu);
    }
}

// ---------- register-blocked fp32 GEMM helpers ----------
__device__ __forceinline__ void fma4(float (&acc)[4], float a, const float4& b) {
    acc[0] += a * b.x; acc[1] += a * b.y; acc[2] += a * b.z; acc[3] += a * b.w;
}

// ---------- GEMM1: x[N,128] @ W1[128,64], scaled by dinv[row] -> xw1s[N,64] fp16 ----------
__global__ __launch_bounds__(256) void k_gemm1(const float* __restrict__ x,
                                               const float* __restrict__ W1,
                                               const float* __restrict__ dinv,
                                               __half* __restrict__ xw1s, int N) {
    __shared__ float sA[64 * NFEAT];   // 32 KB
    __shared__ float sB[NFEAT * NHID]; // 32 KB
    for (int i = threadIdx.x; i < NFEAT * NHID / 4; i += 256)
        ((float4*)sB)[i] = ((const float4*)W1)[i];
    int row0 = blockIdx.x * 64;
    for (int i = threadIdx.x; i < 64 * NFEAT / 4; i += 256) {
        int r = i >> 5, c4 = i & 31;
        int row = row0 + r;
        ((float4*)sA)[i] = (row < N) ? ((const float4*)x)[(long long)row * 32 + c4]
                                     : make_float4(0.f, 0.f, 0.f, 0.f);
    }
    __syncthreads();
    int rg = threadIdx.x >> 4;
    int cg = threadIdx.x & 15;
    int r0 = rg * 4, c0 = cg * 4;
    float acc[4][4] = {};
#pragma unroll 4
    for (int k = 0; k < NFEAT; k += 4) {
        float4 a0 = *(const float4*)&sA[(r0 + 0) * NFEAT + k];
        float4 a1 = *(const float4*)&sA[(r0 + 1) * NFEAT + k];
        float4 a2 = *(const float4*)&sA[(r0 + 2) * NFEAT + k];
        float4 a3 = *(const float4*)&sA[(r0 + 3) * NFEAT + k];
        float4 b0 = *(const float4*)&sB[(k + 0) * NHID + c0];
        float4 b1 = *(const float4*)&sB[(k + 1) * NHID + c0];
        float4 b2v = *(const float4*)&sB[(k + 2) * NHID + c0];
        float4 b3 = *(const float4*)&sB[(k + 3) * NHID + c0];
        fma4(acc[0], a0.x, b0); fma4(acc[0], a0.y, b1); fma4(acc[0], a0.z, b2v); fma4(acc[0], a0.w, b3);
        fma4(acc[1], a1.x, b0); fma4(acc[1], a1.y, b1); fma4(acc[1], a1.z, b2v); fma4(acc[1], a1.w, b3);
        fma4(acc[2], a2.x, b0); fma4(acc[2], a2.y, b1); fma4(acc[2], a2.z, b2v); fma4(acc[2], a2.w, b3);
        fma4(acc[3], a3.x, b0); fma4(acc[3], a3.y, b1); fma4(acc[3], a3.z, b2v); fma4(acc[3], a3.w, b3);
    }
#pragma unroll
    for (int r = 0; r < 4; ++r) {
        int row = row0 + r0 + r;
        if (row < N) {
            float di = dinv[row];
            __half2* dst = (__half2*)&xw1s[(long long)row * NHID + c0];
            dst[0] = __floats2half2_rn(di * acc[r][0], di * acc[r][1]);
            dst[1] = __floats2half2_rn(di * acc[r][2], di * acc[r][3]);
        }
    }
}

// ---------- gather one node's aggregated (pre-scaled) feature sum ----------
// feat2: node rows of 32 half2. Lanes 0-31 process even edges, 32-63 odd.
// Returns float2 of feats (2*li, 2*li+1), valid in lanes 0..31 (li=lane&31).
// Self-loop included.
__device__ __forceinline__ float2 gather_node(const int* __restrict__ off,
                                              const int* __restrict__ esrc,
                                              const __half2* __restrict__ feat2,
                                              int d, int lane) {
    int lo = off[d], hi = off[d + 1];
    int sel = lane >> 5, li = lane & 31;
    float ax = 0.f, ay = 0.f;
    int e = lo;
    for (; e + 16 <= hi; e += 16) {
#pragma unroll
        for (int j = 0; j < 8; ++j) {
            int s = esrc[e + 2 * j + sel];
            float2 v = __half22float2(feat2[(long long)s * 32 + li]);
            ax += v.x; ay += v.y;
        }
    }
    for (; e + 2 <= hi; e += 2) {
        int s = esrc[e + sel];
        float2 v = __half22float2(feat2[(long long)s * 32 + li]);
        ax += v.x; ay += v.y;
    }
    if (e < hi && sel == 0) {
        float2 v = __half22float2(feat2[(long long)esrc[e] * 32 + li]);
        ax += v.x; ay += v.y;
    }
    ax += __shfl_xor(ax, 32);
    ay += __shfl_xor(ay, 32);
    float2 sv = __half22float2(feat2[(long long)d * 32 + li]);   // self loop
    return make_float2(ax + sv.x, ay + sv.y);
}

// ---------- layer-1 aggregation: bias+relu, output pre-scaled fp16 h ----------
__global__ __launch_bounds__(256) void k_agg1(const int* __restrict__ off,
                                              const int* __restrict__ esrc,
                                              const float* __restrict__ dinv,
                                              const __half2* __restrict__ xw1s2,
                                              const float* __restrict__ b1,
                                              __half2* __restrict__ h2, int N) {
    int wave = threadIdx.x >> 6;
    int lane = threadIdx.x & 63;
    int d = blockIdx.x * 4 + wave;
    if (d >= N) return;
    float2 a = gather_node(off, esrc, xw1s2, d, lane);
    if (lane < 32) {
        float dd = dinv[d];
        float2 bias = *(const float2*)&b1[2 * lane];
        float vx = fmaxf(dd * a.x + bias.x, 0.f);
        float vy = fmaxf(dd * a.y + bias.y, 0.f);
        h2[(long long)d * 32 + lane] = __floats2half2_rn(dd * vx, dd * vy);  // pre-scaled
    }
}

// ---------- layer-2 aggregation: fp16 in -> fp32 agg2 ----------
__global__ __launch_bounds__(256) void k_agg2(const int* __restrict__ off,
                                              const int* __restrict__ esrc,
                                              const float* __restrict__ dinv,
                                              const __half2* __restrict__ h2,
                                              float* __restrict__ agg2, int N) {
    int wave = threadIdx.x >> 6;
    int lane = threadIdx.x & 63;
    int d = blockIdx.x * 4 + wave;
    if (d >= N) return;
    float2 a = gather_node(off, esrc, h2, d, lane);
    if (lane < 32) {
        float dd = dinv[d];
        *(float2*)&agg2[(long long)d * NHID + 2 * lane] = make_float2(dd * a.x, dd * a.y);
    }
}

// ---------- GEMM2: agg2[N,64] @ W2[64,128] + b2 -> out[N,128] ----------
__global__ __launch_bounds__(256) void k_gemm2(const float* __restrict__ h,
                                               const float* __restrict__ W2,
                                               const float* __restrict__ b2,
                                               float* __restrict__ out, int N, int ntiles) {
    __shared__ float sB[NHID * NFEAT]; // 32 KB
    __shared__ float sA[64 * NHID];    // 16 KB
    for (int i = threadIdx.x; i < NHID * NFEAT / 4; i += 256)
        ((float4*)sB)[i] = ((const float4*)W2)[i];
    int rg = threadIdx.x >> 5;
    int cg = threadIdx.x & 31;
    int c0 = cg * 4;
    float4 bias = *(const float4*)&b2[c0];
    for (int tile = blockIdx.x; tile < ntiles; tile += gridDim.x) {
        int row0 = tile * 64;
        __syncthreads();
        for (int i = threadIdx.x; i < 64 * NHID / 4; i += 256) {
            int r = i >> 4, c4 = i & 15;
            int row = row0 + r;
            ((float4*)sA)[i] = (row < N) ? ((const float4*)h)[(long long)row * 16 + c4]
                                         : make_float4(0.f, 0.f, 0.f, 0.f);
        }
        __syncthreads();
        float acc[8][4] = {};
#pragma unroll 2
        for (int k = 0; k < NHID; k += 4) {
            float4 b0 = *(const float4*)&sB[(k + 0) * NFEAT + c0];
            float4 b1v = *(const float4*)&sB[(k + 1) * NFEAT + c0];
            float4 b2f = *(const float4*)&sB[(k + 2) * NFEAT + c0];
            float4 b3 = *(const float4*)&sB[(k + 3) * NFEAT + c0];
#pragma unroll
            for (int r = 0; r < 8; ++r) {
                float4 a = *(const float4*)&sA[(rg * 8 + r) * NHID + k];
                fma4(acc[r], a.x, b0); fma4(acc[r], a.y, b1v);
                fma4(acc[r], a.z, b2f); fma4(acc[r], a.w, b3);
            }
        }
#pragma unroll
        for (int r = 0; r < 8; ++r) {
            int row = row0 + rg * 8 + r;
            if (row < N) {
                float4 o = make_float4(acc[r][0] + bias.x, acc[r][1] + bias.y,
                                       acc[r][2] + bias.z, acc[r][3] + bias.w);
                *(float4*)&out[(long long)row * NFEAT + c0] = o;
            }
        }
    }
}

extern "C" void kernel_launch(void* const* d_in, const int* in_sizes, int n_in,
                              void* d_out, int out_size, void* d_ws, size_t ws_size,
                              hipStream_t stream) {
    const float* x  = (const float*)d_in[0];
    const int*   ei = (const int*)d_in[1];
    const float* W1 = (const float*)d_in[2];
    const float* b1 = (const float*)d_in[3];
    const float* W2 = (const float*)d_in[4];
    const float* b2 = (const float*)d_in[5];
    float* out = (float*)d_out;

    const int N = in_sizes[0] / NFEAT;            // 100000
    const long long E = in_sizes[1] / 2;          // 1600000
    const int NB = (N + BNODES - 1) >> BSHIFT;    // 391 buckets

    // workspace layout
    char* w = (char*)d_ws;
    int*      flag    = (int*)w;                       // pad 256 B
    int*      gbhist  = (int*)(w + 256);               // MAXB
    int*      boff    = gbhist + MAXB;                 // MAXB+1
    int*      bcur    = boff + MAXB + 1;               // MAXB
    float*    dinv    = (float*)(bcur + MAXB);         // N
    int*      off     = (int*)(dinv + N);              // N+1
    char*     p       = (char*)(off + N + 1);
    p = (char*)(((uintptr_t)p + 255) & ~(uintptr_t)255);
    unsigned* staging = (unsigned*)p;                  // E * 4 B
    int*      esrc    = (int*)(staging + E);           // E
    __half*   xw1s    = (__half*)(esrc + E);           // N*64 fp16
    __half*   h       = xw1s + (size_t)N * NHID;       // N*64 fp16
    float*    agg2    = (float*)(h + (size_t)N * NHID); // N*64 fp32

    hipMemsetAsync(gbhist, 0, (size_t)NB * sizeof(int), stream);

    k_detect<<<1, 256, 0, stream>>>(ei, 4096, flag);
    k_bhist<<<256, 256, 0, stream>>>(ei, flag, E, gbhist, NB);
    k_bscan<<<1, 256, 0, stream>>>(gbhist, NB, boff, bcur, off + N);
    long long perblk = (E + 511) / 512;
    k_partition<<<512, 256, 0, stream>>>(ei, flag, E, bcur, staging, NB, perblk);
    k_bucket<<<NB, 256, 0, stream>>>(staging, boff, N, off, esrc, dinv);

    k_gemm1<<<(N + 63) / 64, 256, 0, stream>>>(x, W1, dinv, xw1s, N);

    k_agg1<<<(N + 3) / 4, 256, 0, stream>>>(off, esrc, dinv, (const __half2*)xw1s,
                                            b1, (__half2*)h, N);
    k_agg2<<<(N + 3) / 4, 256, 0, stream>>>(off, esrc, dinv, (const __half2*)h,
                                            agg2, N);

    int ntiles = (N + 63) / 64;
    int g2grid = ntiles < 768 ? ntiles : 768;
    k_gemm2<<<g2grid, 256, 0, stream>>>(agg2, W2, b2, out, N, ntiles);
}

// Round 7
// 325.001 us; speedup vs baseline: 1.4338x; 1.1172x over previous
//
#include <hip/hip_runtime.h>
#include <hip/hip_fp16.h>

#define NFEAT 128
#define NHID 64
#define MAXB 1024          // max dst buckets (node>>8), supports N<=262144
#define BSHIFT 8
#define BNODES 256
#define PBLK 512           // partition/hist blocks

// ---------- edge-index dtype detection ----------
// JAX reference says int64 but default JAX config downcasts to int32.
// Little-endian int64 with values < 2^31 => every odd int32 word is 0.
__global__ void k_detect(const int* __restrict__ ei_words, int nwords, int* flag) {
    __shared__ int s_or;
    if (threadIdx.x == 0) s_or = 0;
    __syncthreads();
    int acc = 0;
    for (int i = 1 + 2 * (int)threadIdx.x; i < nwords; i += 2 * (int)blockDim.x)
        acc |= ei_words[i];
    atomicOr(&s_or, acc);
    __syncthreads();
    if (threadIdx.x == 0) *flag = (s_or == 0) ? 1 : 0;
}

__device__ __forceinline__ int edge_idx(const int* __restrict__ ei, int is64,
                                        long long E, long long e, int which) {
    long long pos = which ? (E + e) : e;
    return is64 ? ei[2 * pos] : ei[pos];
}

// ---------- bucket histogram (contiguous chunks; saves per-block hist) ----------
__global__ __launch_bounds__(256) void k_bhist(const int* __restrict__ ei,
                                               const int* __restrict__ flag,
                                               long long E, int* gbhist,
                                               int* __restrict__ blockhist,
                                               int NB, long long perblk) {
    __shared__ int hist[MAXB];
    for (int i = threadIdx.x; i < NB; i += 256) hist[i] = 0;
    __syncthreads();
    int is64 = *flag;
    long long lo = (long long)blockIdx.x * perblk;
    long long hi = lo + perblk; if (hi > E) hi = E;
    for (long long e = lo + threadIdx.x; e < hi; e += 256) {
        int d = edge_idx(ei, is64, E, e, 1);
        atomicAdd(&hist[d >> BSHIFT], 1);
    }
    __syncthreads();
    int* bh = blockhist + (size_t)blockIdx.x * MAXB;
    for (int i = threadIdx.x; i < NB; i += 256) {
        int v = hist[i];
        bh[i] = v;
        if (v) atomicAdd(&gbhist[i], v);
    }
}

// ---------- scan bucket totals (1 block); also writes off[N]=E ----------
__global__ __launch_bounds__(256) void k_bscan(const int* __restrict__ gbhist, int NB,
                                               int* boff, int* bcur, int* offN) {
    __shared__ int s[256];
    int t = threadIdx.x;
    int v[4]; int sum = 0;
#pragma unroll
    for (int j = 0; j < 4; ++j) {
        int i = t * 4 + j;
        v[j] = (i < NB) ? gbhist[i] : 0;
        sum += v[j];
    }
    s[t] = sum;
    __syncthreads();
    for (int d = 1; d < 256; d <<= 1) {
        int val = (t >= d) ? s[t - d] : 0;
        __syncthreads();
        s[t] += val;
        __syncthreads();
    }
    int run = s[t] - sum;   // exclusive
#pragma unroll
    for (int j = 0; j < 4; ++j) {
        int i = t * 4 + j;
        if (i <= NB) boff[i] = run;
        if (i < NB)  bcur[i] = run;
        run += v[j];
    }
    if (t == 255) *offN = s[255];   // off[N] = E
}

// ---------- partition edges into dst buckets (reuses blockhist; 1 edge pass) ----------
// record = src | (dst&255)<<24  (requires src < 2^24)
__global__ __launch_bounds__(256) void k_partition(const int* __restrict__ ei,
                                                   const int* __restrict__ flag,
                                                   long long E, int* bcur,
                                                   const int* __restrict__ blockhist,
                                                   unsigned* __restrict__ staging,
                                                   int NB, long long perblk) {
    __shared__ int cur[MAXB];
    const int* bh = blockhist + (size_t)blockIdx.x * MAXB;
    for (int i = threadIdx.x; i < NB; i += 256) {
        int v = bh[i];
        cur[i] = v ? atomicAdd(&bcur[i], v) : 0;
    }
    __syncthreads();
    long long lo = (long long)blockIdx.x * perblk;
    long long hi = lo + perblk; if (hi > E) hi = E;
    int is64 = *flag;
    for (long long e = lo + threadIdx.x; e < hi; e += 256) {
        int s = edge_idx(ei, is64, E, e, 0);
        int d = edge_idx(ei, is64, E, e, 1);
        int pos = atomicAdd(&cur[d >> BSHIFT], 1);
        staging[pos] = (unsigned)s | ((unsigned)(d & (BNODES - 1)) << 24);
    }
}

// ---------- per-bucket CSR: node counts, scan, fill esrc; emit off & dinv ----------
__global__ __launch_bounds__(256) void k_bucket(const unsigned* __restrict__ staging,
                                                const int* __restrict__ boff,
                                                int N, int* off, int* esrc, float* dinv) {
    __shared__ int cnt_s[BNODES];
    __shared__ int scan_s[BNODES];
    int b = blockIdx.x;
    int base = b << BSHIFT;
    int t = threadIdx.x;
    cnt_s[t] = 0;
    __syncthreads();
    int lo = boff[b], hi = boff[b + 1];
    for (int e = lo + t; e < hi; e += 256)
        atomicAdd(&cnt_s[staging[e] >> 24], 1);
    __syncthreads();
    int v = cnt_s[t];
    scan_s[t] = v;
    __syncthreads();
    for (int d = 1; d < 256; d <<= 1) {
        int val = (t >= d) ? scan_s[t - d] : 0;
        __syncthreads();
        scan_s[t] += val;
        __syncthreads();
    }
    int excl = scan_s[t] - v;
    int node = base + t;
    if (node < N) {
        off[node] = lo + excl;
        dinv[node] = rsqrtf((float)v + 1.0f);   // +1 self loop
    }
    __syncthreads();
    cnt_s[t] = lo + excl;   // reuse as cursor
    __syncthreads();
    for (int e = lo + t; e < hi; e += 256) {
        unsigned sd = staging[e];
        int pos = atomicAdd(&cnt_s[sd >> 24], 1);
        esrc[pos] = (int)(sd & 0xFFFFFFu);
    }
}

// ---------- register-blocked fp32 GEMM helpers ----------
__device__ __forceinline__ void fma4(float (&acc)[4], float a, const float4& b) {
    acc[0] += a * b.x; acc[1] += a * b.y; acc[2] += a * b.z; acc[3] += a * b.w;
}

// ---------- GEMM1: x[N,128] @ W1[128,64], scaled by dinv[row] -> xw1s[N,64] fp16 ----------
__global__ __launch_bounds__(256) void k_gemm1(const float* __restrict__ x,
                                               const float* __restrict__ W1,
                                               const float* __restrict__ dinv,
                                               __half* __restrict__ xw1s, int N) {
    __shared__ float sA[64 * NFEAT];   // 32 KB
    __shared__ float sB[NFEAT * NHID]; // 32 KB
    for (int i = threadIdx.x; i < NFEAT * NHID / 4; i += 256)
        ((float4*)sB)[i] = ((const float4*)W1)[i];
    int row0 = blockIdx.x * 64;
    for (int i = threadIdx.x; i < 64 * NFEAT / 4; i += 256) {
        int r = i >> 5, c4 = i & 31;
        int row = row0 + r;
        ((float4*)sA)[i] = (row < N) ? ((const float4*)x)[(long long)row * 32 + c4]
                                     : make_float4(0.f, 0.f, 0.f, 0.f);
    }
    __syncthreads();
    int rg = threadIdx.x >> 4;
    int cg = threadIdx.x & 15;
    int r0 = rg * 4, c0 = cg * 4;
    float acc[4][4] = {};
#pragma unroll 4
    for (int k = 0; k < NFEAT; k += 4) {
        float4 a0 = *(const float4*)&sA[(r0 + 0) * NFEAT + k];
        float4 a1 = *(const float4*)&sA[(r0 + 1) * NFEAT + k];
        float4 a2 = *(const float4*)&sA[(r0 + 2) * NFEAT + k];
        float4 a3 = *(const float4*)&sA[(r0 + 3) * NFEAT + k];
        float4 b0 = *(const float4*)&sB[(k + 0) * NHID + c0];
        float4 b1 = *(const float4*)&sB[(k + 1) * NHID + c0];
        float4 b2v = *(const float4*)&sB[(k + 2) * NHID + c0];
        float4 b3 = *(const float4*)&sB[(k + 3) * NHID + c0];
        fma4(acc[0], a0.x, b0); fma4(acc[0], a0.y, b1); fma4(acc[0], a0.z, b2v); fma4(acc[0], a0.w, b3);
        fma4(acc[1], a1.x, b0); fma4(acc[1], a1.y, b1); fma4(acc[1], a1.z, b2v); fma4(acc[1], a1.w, b3);
        fma4(acc[2], a2.x, b0); fma4(acc[2], a2.y, b1); fma4(acc[2], a2.z, b2v); fma4(acc[2], a2.w, b3);
        fma4(acc[3], a3.x, b0); fma4(acc[3], a3.y, b1); fma4(acc[3], a3.z, b2v); fma4(acc[3], a3.w, b3);
    }
#pragma unroll
    for (int r = 0; r < 4; ++r) {
        int row = row0 + r0 + r;
        if (row < N) {
            float di = dinv[row];
            __half2* dst = (__half2*)&xw1s[(long long)row * NHID + c0];
            dst[0] = __floats2half2_rn(di * acc[r][0], di * acc[r][1]);
            dst[1] = __floats2half2_rn(di * acc[r][2], di * acc[r][3]);
        }
    }
}

// ---------- 8-lane gather: lane group g=lane>>3 handles edge e+g; li=lane&7 ----------
// Each lane loads a uint4 (8 fp16) = 1/8 row; one instruction = 8 rows = 8 lines.
__device__ __forceinline__ void addhalf8(float2 (&acc)[4], uint4 p) {
    const __half2* hh = (const __half2*)&p;
#pragma unroll
    for (int j = 0; j < 4; ++j) {
        float2 v = __half22float2(hh[j]);
        acc[j].x += v.x; acc[j].y += v.y;
    }
}

__device__ __forceinline__ void gather_node8(const int* __restrict__ off,
                                             const int* __restrict__ esrc,
                                             const uint4* __restrict__ feat4,
                                             int d, int g, int li, float2 (&acc)[4]) {
#pragma unroll
    for (int j = 0; j < 4; ++j) acc[j] = make_float2(0.f, 0.f);
    int lo = off[d], hi = off[d + 1];
    int e = lo;
    for (; e + 16 <= hi; e += 16) {
        int s0 = esrc[e + g];
        int s1 = esrc[e + 8 + g];
        uint4 p0 = feat4[(size_t)s0 * 8 + li];
        uint4 p1 = feat4[(size_t)s1 * 8 + li];
        addhalf8(acc, p0);
        addhalf8(acc, p1);
    }
    for (; e + 8 <= hi; e += 8) {
        uint4 p0 = feat4[(size_t)esrc[e + g] * 8 + li];
        addhalf8(acc, p0);
    }
    int rem = hi - e;
    if (g < rem) {
        uint4 p0 = feat4[(size_t)esrc[e + g] * 8 + li];
        addhalf8(acc, p0);
    }
    // reduce across the 8 groups (lanes differing in bits 3..5)
#pragma unroll
    for (int m = 8; m <= 32; m <<= 1) {
#pragma unroll
        for (int j = 0; j < 4; ++j) {
            acc[j].x += __shfl_xor(acc[j].x, m);
            acc[j].y += __shfl_xor(acc[j].y, m);
        }
    }
}

// ---------- layer-1 aggregation: bias+relu, output pre-scaled fp16 h ----------
__global__ __launch_bounds__(256) void k_agg1(const int* __restrict__ off,
                                              const int* __restrict__ esrc,
                                              const float* __restrict__ dinv,
                                              const uint4* __restrict__ xw1s4,
                                              const float* __restrict__ b1,
                                              uint4* __restrict__ h4, int N) {
    int wave = threadIdx.x >> 6;
    int lane = threadIdx.x & 63;
    int d = blockIdx.x * 4 + wave;
    if (d >= N) return;
    int g = lane >> 3, li = lane & 7;
    float2 acc[4];
    gather_node8(off, esrc, xw1s4, d, g, li, acc);
    if (g == 0) {
        uint4 sp = xw1s4[(size_t)d * 8 + li];   // self loop (pre-scaled)
        addhalf8(acc, sp);
        float dd = dinv[d];
        float4 bA = ((const float4*)b1)[li * 2 + 0];
        float4 bB = ((const float4*)b1)[li * 2 + 1];
        float v0 = fmaxf(dd * acc[0].x + bA.x, 0.f);
        float v1 = fmaxf(dd * acc[0].y + bA.y, 0.f);
        float v2 = fmaxf(dd * acc[1].x + bA.z, 0.f);
        float v3 = fmaxf(dd * acc[1].y + bA.w, 0.f);
        float v4 = fmaxf(dd * acc[2].x + bB.x, 0.f);
        float v5 = fmaxf(dd * acc[2].y + bB.y, 0.f);
        float v6 = fmaxf(dd * acc[3].x + bB.z, 0.f);
        float v7 = fmaxf(dd * acc[3].y + bB.w, 0.f);
        __half2 o[4];
        o[0] = __floats2half2_rn(dd * v0, dd * v1);   // pre-scaled for layer 2
        o[1] = __floats2half2_rn(dd * v2, dd * v3);
        o[2] = __floats2half2_rn(dd * v4, dd * v5);
        o[3] = __floats2half2_rn(dd * v6, dd * v7);
        h4[(size_t)d * 8 + li] = *(const uint4*)o;
    }
}

// ---------- layer-2 aggregation: fp16 in -> fp32 agg2 ----------
__global__ __launch_bounds__(256) void k_agg2(const int* __restrict__ off,
                                              const int* __restrict__ esrc,
                                              const float* __restrict__ dinv,
                                              const uint4* __restrict__ h4,
                                              float* __restrict__ agg2, int N) {
    int wave = threadIdx.x >> 6;
    int lane = threadIdx.x & 63;
    int d = blockIdx.x * 4 + wave;
    if (d >= N) return;
    int g = lane >> 3, li = lane & 7;
    float2 acc[4];
    gather_node8(off, esrc, h4, d, g, li, acc);
    if (g == 0) {
        uint4 sp = h4[(size_t)d * 8 + li];   // self loop (pre-scaled)
        addhalf8(acc, sp);
        float dd = dinv[d];
        float4* row = (float4*)&agg2[(size_t)d * NHID];
        row[li * 2 + 0] = make_float4(dd * acc[0].x, dd * acc[0].y, dd * acc[1].x, dd * acc[1].y);
        row[li * 2 + 1] = make_float4(dd * acc[2].x, dd * acc[2].y, dd * acc[3].x, dd * acc[3].y);
    }
}

// ---------- GEMM2: agg2[N,64] @ W2[64,128] + b2 -> out[N,128] ----------
__global__ __launch_bounds__(256) void k_gemm2(const float* __restrict__ h,
                                               const float* __restrict__ W2,
                                               const float* __restrict__ b2,
                                               float* __restrict__ out, int N, int ntiles) {
    __shared__ float sB[NHID * NFEAT]; // 32 KB
    __shared__ float sA[64 * NHID];    // 16 KB
    for (int i = threadIdx.x; i < NHID * NFEAT / 4; i += 256)
        ((float4*)sB)[i] = ((const float4*)W2)[i];
    int rg = threadIdx.x >> 5;
    int cg = threadIdx.x & 31;
    int c0 = cg * 4;
    float4 bias = *(const float4*)&b2[c0];
    for (int tile = blockIdx.x; tile < ntiles; tile += gridDim.x) {
        int row0 = tile * 64;
        __syncthreads();
        for (int i = threadIdx.x; i < 64 * NHID / 4; i += 256) {
            int r = i >> 4, c4 = i & 15;
            int row = row0 + r;
            ((float4*)sA)[i] = (row < N) ? ((const float4*)h)[(long long)row * 16 + c4]
                                         : make_float4(0.f, 0.f, 0.f, 0.f);
        }
        __syncthreads();
        float acc[8][4] = {};
#pragma unroll 2
        for (int k = 0; k < NHID; k += 4) {
            float4 b0 = *(const float4*)&sB[(k + 0) * NFEAT + c0];
            float4 b1v = *(const float4*)&sB[(k + 1) * NFEAT + c0];
            float4 b2f = *(const float4*)&sB[(k + 2) * NFEAT + c0];
            float4 b3 = *(const float4*)&sB[(k + 3) * NFEAT + c0];
#pragma unroll
            for (int r = 0; r < 8; ++r) {
                float4 a = *(const float4*)&sA[(rg * 8 + r) * NHID + k];
                fma4(acc[r], a.x, b0); fma4(acc[r], a.y, b1v);
                fma4(acc[r], a.z, b2f); fma4(acc[r], a.w, b3);
            }
        }
#pragma unroll
        for (int r = 0; r < 8; ++r) {
            int row = row0 + rg * 8 + r;
            if (row < N) {
                float4 o = make_float4(acc[r][0] + bias.x, acc[r][1] + bias.y,
                                       acc[r][2] + bias.z, acc[r][3] + bias.w);
                *(float4*)&out[(long long)row * NFEAT + c0] = o;
            }
        }
    }
}

static inline char* align256(char* p) {
    return (char*)(((uintptr_t)p + 255) & ~(uintptr_t)255);
}

extern "C" void kernel_launch(void* const* d_in, const int* in_sizes, int n_in,
                              void* d_out, int out_size, void* d_ws, size_t ws_size,
                              hipStream_t stream) {
    const float* x  = (const float*)d_in[0];
    const int*   ei = (const int*)d_in[1];
    const float* W1 = (const float*)d_in[2];
    const float* b1 = (const float*)d_in[3];
    const float* W2 = (const float*)d_in[4];
    const float* b2 = (const float*)d_in[5];
    float* out = (float*)d_out;

    const int N = in_sizes[0] / NFEAT;            // 100000
    const long long E = in_sizes[1] / 2;          // 1600000
    const int NB = (N + BNODES - 1) >> BSHIFT;    // 391 buckets

    // workspace layout (each region 256B-aligned where it matters)
    char* w = (char*)d_ws;
    int*      flag      = (int*)w;                        // pad 256 B
    int*      gbhist    = (int*)(w + 256);                // MAXB
    int*      boff      = gbhist + MAXB;                  // MAXB+1
    int*      bcur      = boff + MAXB + 1;                // MAXB
    int*      blockhist = bcur + MAXB;                    // PBLK*MAXB (2 MB)
    float*    dinv      = (float*)(blockhist + (size_t)PBLK * MAXB);  // N
    int*      off       = (int*)(dinv + N);               // N+1
    char*     p         = align256((char*)(off + N + 1));
    unsigned* staging   = (unsigned*)p;                   // E * 4 B
    p = align256((char*)(staging + E));
    int*      esrc      = (int*)p;                        // E
    p = align256((char*)(esrc + E));
    __half*   xw1s      = (__half*)p;                     // N*64 fp16
    p = align256((char*)(xw1s + (size_t)N * NHID));
    __half*   h         = (__half*)p;                     // N*64 fp16
    p = align256((char*)(h + (size_t)N * NHID));
    float*    agg2      = (float*)p;                      // N*64 fp32

    hipMemsetAsync(gbhist, 0, (size_t)NB * sizeof(int), stream);

    long long perblk = (E + PBLK - 1) / PBLK;
    k_detect<<<1, 256, 0, stream>>>(ei, 4096, flag);
    k_bhist<<<PBLK, 256, 0, stream>>>(ei, flag, E, gbhist, blockhist, NB, perblk);
    k_bscan<<<1, 256, 0, stream>>>(gbhist, NB, boff, bcur, off + N);
    k_partition<<<PBLK, 256, 0, stream>>>(ei, flag, E, bcur, blockhist, staging, NB, perblk);
    k_bucket<<<NB, 256, 0, stream>>>(staging, boff, N, off, esrc, dinv);

    k_gemm1<<<(N + 63) / 64, 256, 0, stream>>>(x, W1, dinv, xw1s, N);

    k_agg1<<<(N + 3) / 4, 256, 0, stream>>>(off, esrc, dinv, (const uint4*)xw1s,
                                            b1, (uint4*)h, N);
    k_agg2<<<(N + 3) / 4, 256, 0, stream>>>(off, esrc, dinv, (const uint4*)h,
                                            agg2, N);

    int ntiles = (N + 63) / 64;
    int g2grid = ntiles < 768 ? ntiles : 768;
    k_gemm2<<<g2grid, 256, 0, stream>>>(agg2, W2, b2, out, N, ntiles);
}